// Round 8
// baseline (1355.739 us; speedup 1.0000x reference)
//
#include <hip/hip_runtime.h>
#include <math.h>

#define N_ROWS 16384
#define DIM    2048
#define K_CENT 1000
#define CDIM   2049   // D+1
#define BM     128
#define BN     128
#define BK     16
#define NTILES 8      // center tiles of 128 (covers 1000 with masking)

// ---------------- kernel 1: per-row inverse norm (including appended 1) ----
__global__ __launch_bounds__(256) void rnorm_kernel(const float* __restrict__ feats,
                                                    float* __restrict__ rnorm) {
    const int row = blockIdx.x;
    const int t = threadIdx.x;
    const float4* p4 = (const float4*)(feats + (size_t)row * DIM);
    float4 v0 = p4[t];
    float4 v1 = p4[t + 256];
    float s = v0.x*v0.x + v0.y*v0.y + v0.z*v0.z + v0.w*v0.w
            + v1.x*v1.x + v1.y*v1.y + v1.z*v1.z + v1.w*v1.w;
    #pragma unroll
    for (int m = 1; m < 64; m <<= 1) s += __shfl_xor(s, m, 64);
    __shared__ float ws[4];
    if ((t & 63) == 0) ws[t >> 6] = s;
    __syncthreads();
    if (t == 0) {
        float tot = ws[0] + ws[1] + ws[2] + ws[3] + 1.0f;  // +1 for appended ones col
        rnorm[row] = 1.0f / sqrtf(tot);
    }
}

// ---------------- kernel 2: per-center squared norm (all D+1 elems) --------
__global__ __launch_bounds__(256) void cn2_kernel(const float* __restrict__ initc,
                                                  float* __restrict__ cn2) {
    const int j = blockIdx.x;
    const int t = threadIdx.x;
    const float* p = initc + (size_t)j * CDIM;
    float s = 0.f;
    for (int i = t; i < CDIM; i += 256) { float v = p[i]; s = fmaf(v, v, s); }
    #pragma unroll
    for (int m = 1; m < 64; m <<= 1) s += __shfl_xor(s, m, 64);
    __shared__ float ws[4];
    if ((t & 63) == 0) ws[t >> 6] = s;
    __syncthreads();
    if (t == 0) cn2[j] = ws[0] + ws[1] + ws[2] + ws[3];
}

// ---------------- kernel 3: tiled fp32 GEMM + fused score + partial argmin -
// 256 threads, 128x128 tile, 8x8 microtile.
// Thread (tx,ty) = (t&15, t>>4) owns rows ty*8..ty*8+7 and centers
// {tx*4+j}∪{64+tx*4+j} (split to keep b-fragment LDS reads conflict-free).
__global__ __launch_bounds__(256) void dist_kernel(const float* __restrict__ feats,
                                                   const float* __restrict__ initc,
                                                   const float* __restrict__ rnorm,
                                                   const float* __restrict__ cn2,
                                                   float* __restrict__ pval,
                                                   int* __restrict__ pidx) {
    __shared__ __align__(16) float As[BK][BM + 4];  // [k][m], padded
    __shared__ __align__(16) float Bs[BK][BN + 4];  // [k][n], padded

    const int bm = blockIdx.x;           // 0..127
    const int bn = blockIdx.y;           // 0..7
    const int t  = threadIdx.x;
    const int tx = t & 15;               // center group
    const int ty = t >> 4;               // row group (8 rows)
    const int rowBase  = bm * BM;
    const int centBase = bn * BN;

    float acc[8][8];
    #pragma unroll
    for (int i = 0; i < 8; ++i)
        #pragma unroll
        for (int j = 0; j < 8; ++j) acc[i][j] = 0.f;

    const int ar  = t >> 2;              // 0..63 (A staging row)
    const int ac4 = (t & 3) << 2;        // 0,4,8,12
    const int bc  = t >> 4;              // 0..15 (B staging center)
    const int bcol = t & 15;             // 0..15

    // center index of thread-local column j
    auto cidx = [&](int j) { return (j < 4) ? (tx * 4 + j) : (64 + tx * 4 + (j - 4)); };

    for (int k0 = 0; k0 < DIM; k0 += BK) {
        // stage A: 128 rows x 16 cols, float4 coalesced
        #pragma unroll
        for (int p = 0; p < 2; ++p) {
            int row = p * 64 + ar;
            const float4 v = *(const float4*)(feats + (size_t)(rowBase + row) * DIM + k0 + ac4);
            As[ac4 + 0][row] = v.x;
            As[ac4 + 1][row] = v.y;
            As[ac4 + 2][row] = v.z;
            As[ac4 + 3][row] = v.w;
        }
        // stage B: 128 centers x 16 cols, scalar (odd row stride 2049)
        #pragma unroll
        for (int p = 0; p < 8; ++p) {
            int cent = p * 16 + bc;
            int gj = centBase + cent;
            Bs[bcol][cent] = (gj < K_CENT) ? initc[(size_t)gj * CDIM + k0 + bcol] : 0.f;
        }
        __syncthreads();
        #pragma unroll
        for (int kk = 0; kk < BK; ++kk) {
            float a[8], b[8];
            *(float4*)&a[0] = *(const float4*)&As[kk][ty * 8];
            *(float4*)&a[4] = *(const float4*)&As[kk][ty * 8 + 4];
            *(float4*)&b[0] = *(const float4*)&Bs[kk][tx * 4];        // conflict-free (16B stride)
            *(float4*)&b[4] = *(const float4*)&Bs[kk][64 + tx * 4];
            #pragma unroll
            for (int i = 0; i < 8; ++i)
                #pragma unroll
                for (int j = 0; j < 8; ++j)
                    acc[i][j] = fmaf(a[i], b[j], acc[i][j]);
        }
        __syncthreads();
    }

    // epilogue: score = cn2[j] - 2*rnorm[i]*(dot + c_last[j]); partial argmin
    float rn[8];
    #pragma unroll
    for (int i = 0; i < 8; ++i) rn[i] = rnorm[rowBase + ty * 8 + i];
    float cl[8], c2[8];
    #pragma unroll
    for (int j = 0; j < 8; ++j) {
        int gj = centBase + cidx(j);
        cl[j] = (gj < K_CENT) ? initc[(size_t)gj * CDIM + DIM] : 0.f;
        c2[j] = (gj < K_CENT) ? cn2[gj] : INFINITY;
    }
    #pragma unroll
    for (int i = 0; i < 8; ++i) {
        float bestv = INFINITY;
        int   besti = 0x7fffffff;
        #pragma unroll
        for (int j = 0; j < 8; ++j) {   // cidx ascending in j => first-min kept
            int gj = centBase + cidx(j);
            float v = (gj < K_CENT) ? (c2[j] - 2.0f * rn[i] * (acc[i][j] + cl[j])) : INFINITY;
            if (v < bestv) { bestv = v; besti = gj; }
        }
        // reduce across the 16 tx lanes (consecutive lanes within the wave)
        #pragma unroll
        for (int m = 1; m < 16; m <<= 1) {
            float ov = __shfl_xor(bestv, m, 64);
            int   oi = __shfl_xor(besti, m, 64);
            if (ov < bestv || (ov == bestv && oi < besti)) { bestv = ov; besti = oi; }
        }
        if (tx == 0) {
            int row = rowBase + ty * 8 + i;
            pval[row * NTILES + bn] = bestv;
            pidx[row * NTILES + bn] = besti;
        }
    }
}

// ---------------- kernel 4: final argmin over 8 tile partials --------------
__global__ __launch_bounds__(256) void argmin_kernel(const float* __restrict__ pval,
                                                     const int* __restrict__ pidx,
                                                     const int* __restrict__ labels,
                                                     int* __restrict__ out) {
    const int i = blockIdx.x * 256 + threadIdx.x;
    float bestv = INFINITY;
    int   besti = 0x7fffffff;
    #pragma unroll
    for (int bn = 0; bn < NTILES; ++bn) {
        float v = pval[i * NTILES + bn];
        int  ix = pidx[i * NTILES + bn];
        if (v < bestv || (v == bestv && ix < besti)) { bestv = v; besti = ix; }
    }
    out[i] = labels[besti];
}

extern "C" void kernel_launch(void* const* d_in, const int* in_sizes, int n_in,
                              void* d_out, int out_size, void* d_ws, size_t ws_size,
                              hipStream_t stream) {
    const float* feats  = (const float*)d_in[0];   // [16384, 2048] fp32
    const float* initc  = (const float*)d_in[1];   // [1000, 2049] fp32
    const int*   labels = (const int*)d_in[2];     // [1000] int32 (arange)
    int* out = (int*)d_out;                        // [16384] int32

    char* ws = (char*)d_ws;
    float* rnorm = (float*)(ws);                          // 16384 f (64 KiB)
    float* cn2   = (float*)(ws + 65536);                  // 4 KiB
    float* pval  = (float*)(ws + 73728);                  // 16384*8 f (512 KiB)
    int*   pidx  = (int*)  (ws + 73728 + 524288);         // 16384*8 i (512 KiB)

    rnorm_kernel<<<N_ROWS, 256, 0, stream>>>(feats, rnorm);
    cn2_kernel<<<K_CENT, 256, 0, stream>>>(initc, cn2);
    dim3 grid(N_ROWS / BM, NTILES);
    dist_kernel<<<grid, 256, 0, stream>>>(feats, initc, rnorm, cn2, pval, pidx);
    argmin_kernel<<<N_ROWS / 256, 256, 0, stream>>>(pval, pidx, labels, out);
}

// Round 9
// 513.880 us; speedup vs baseline: 2.6382x; 2.6382x over previous
//
#include <hip/hip_runtime.h>
#include <math.h>

#define N_ROWS 16384
#define DIM    2048
#define K_CENT 1000
#define KPAD   1024
#define CDIM   2049   // D+1

// ---------------- MFMA-path workspace layout (bytes) ----------------
#define WS_AH   ((size_t)0)
#define WS_AL   ((size_t)67108864)
#define WS_BH   ((size_t)134217728)
#define WS_BL   ((size_t)138412032)
#define WS_RN   ((size_t)142606336)
#define WS_CN2  ((size_t)142671872)
#define WS_CL   ((size_t)142675968)
#define WS_PV   ((size_t)142680064)
#define WS_PI   ((size_t)143728640)
#define WS_NEED ((size_t)144777216)

typedef __attribute__((ext_vector_type(8))) short bf16x8;   // 8 bf16 (4 VGPR)
typedef __attribute__((ext_vector_type(4))) float f32x4;    // MFMA acc

__device__ __forceinline__ unsigned short f2bf(float x){    // RNE fp32->bf16
  unsigned int u = __float_as_uint(x);
  u += 0x7fffu + ((u >> 16) & 1u);
  return (unsigned short)(u >> 16);
}
__device__ __forceinline__ float bf2f(unsigned short h){
  return __uint_as_float(((unsigned int)h) << 16);
}

typedef const __attribute__((address_space(1))) void gv_t;
typedef __attribute__((address_space(3))) void lv_t;
__device__ __forceinline__ void gload16(const void* g, void* l){
  __builtin_amdgcn_global_load_lds((gv_t*)g, (lv_t*)l, 16, 0, 0);
}

// ---------------- prep: feats -> (Ah,Al) bf16 split + rnorm ----------------
__global__ __launch_bounds__(256) void prep_feats(const float* __restrict__ feats,
    unsigned short* __restrict__ Ah, unsigned short* __restrict__ Al,
    float* __restrict__ rnorm){
  const int row = blockIdx.x, t = threadIdx.x;
  const float4* p4 = (const float4*)(feats + (size_t)row * DIM);
  float4 v0 = p4[t], v1 = p4[t + 256];
  float e0[4] = {v0.x, v0.y, v0.z, v0.w};
  float e1[4] = {v1.x, v1.y, v1.z, v1.w};
  float s = 0.f;
  unsigned short h0[4], l0[4], h1[4], l1[4];
  #pragma unroll
  for (int q = 0; q < 4; ++q){
    s = fmaf(e0[q], e0[q], s); s = fmaf(e1[q], e1[q], s);
    unsigned short h = f2bf(e0[q]); h0[q] = h; l0[q] = f2bf(e0[q] - bf2f(h));
    h = f2bf(e1[q]); h1[q] = h; l1[q] = f2bf(e1[q] - bf2f(h));
  }
  *(ushort4*)(Ah + (size_t)row*DIM + t*4)        = make_ushort4(h0[0],h0[1],h0[2],h0[3]);
  *(ushort4*)(Ah + (size_t)row*DIM + (t+256)*4)  = make_ushort4(h1[0],h1[1],h1[2],h1[3]);
  *(ushort4*)(Al + (size_t)row*DIM + t*4)        = make_ushort4(l0[0],l0[1],l0[2],l0[3]);
  *(ushort4*)(Al + (size_t)row*DIM + (t+256)*4)  = make_ushort4(l1[0],l1[1],l1[2],l1[3]);
  #pragma unroll
  for (int mm = 1; mm < 64; mm <<= 1) s += __shfl_xor(s, mm, 64);
  __shared__ float wsm[4];
  if ((t & 63) == 0) wsm[t >> 6] = s;
  __syncthreads();
  if (t == 0) rnorm[row] = 1.0f / sqrtf(wsm[0]+wsm[1]+wsm[2]+wsm[3] + 1.0f);
}

// ---------------- prep: centers -> (Bh,Bl) split + cn2 + bias col ----------
__global__ __launch_bounds__(256) void prep_cent(const float* __restrict__ initc,
    unsigned short* __restrict__ Bh, unsigned short* __restrict__ Bl,
    float* __restrict__ cn2, float* __restrict__ cl){
  const int j = blockIdx.x, t = threadIdx.x;
  __shared__ float wsm[4];
  if (j < K_CENT){
    const float* p = initc + (size_t)j * CDIM;   // odd stride -> scalar loads
    float s = 0.f;
    for (int i = t; i < CDIM; i += 256){
      float x = p[i];
      s = fmaf(x, x, s);
      if (i < DIM){
        unsigned short h = f2bf(x);
        Bh[(size_t)j*DIM + i] = h;
        Bl[(size_t)j*DIM + i] = f2bf(x - bf2f(h));
      } else {
        cl[j] = x;                                // bias column c[2048]
      }
    }
    #pragma unroll
    for (int mm = 1; mm < 64; mm <<= 1) s += __shfl_xor(s, mm, 64);
    if ((t & 63) == 0) wsm[t >> 6] = s;
    __syncthreads();
    if (t == 0) cn2[j] = wsm[0] + wsm[1] + wsm[2] + wsm[3];
  } else {                                        // padded centers 1000..1023
    for (int i = t; i < DIM; i += 256){
      Bh[(size_t)j*DIM + i] = 0;
      Bl[(size_t)j*DIM + i] = 0;
    }
    if (t == 0){ cn2[j] = INFINITY; cl[j] = 0.f; }
  }
}

// ---------------- MFMA GEMM (bf16x3) + fused score + partial argmin --------
// 128x128 tile, 4 waves in 2x2; wave = 64x64 = 4x4 fragments of 16x16x32.
// LDS per operand tile: [kb=4][row=128][8] bf16 (16B chunks, linear for
// global_load_lds; frag reads land 2-way on banks). 3 MFMAs per frag pair:
// Ah*Bh + Ah*Bl + Al*Bh (err ~1e-5 << argmin margins).
__global__ __launch_bounds__(256) void dist_mfma(
    const unsigned short* __restrict__ Ah, const unsigned short* __restrict__ Al,
    const unsigned short* __restrict__ Bh, const unsigned short* __restrict__ Bl,
    const float* __restrict__ rnorm, const float* __restrict__ cn2,
    const float* __restrict__ cl, float* __restrict__ pval, int* __restrict__ pidx){
  __shared__ char smem[32768];   // Ah:0 Al:8192 Bh:16384 Bl:24576
  const int t = threadIdx.x;
  const int l = t & 63;
  const int w = t >> 6;
  const int wr = w >> 1, wc = w & 1;
  const int rowBase = blockIdx.x * 128, colBase = blockIdx.y * 128;
  const int kb = l >> 4, lr = l & 15;

  f32x4 acc[4][4];
  #pragma unroll
  for (int m = 0; m < 4; ++m)
    #pragma unroll
    for (int n = 0; n < 4; ++n)
      #pragma unroll
      for (int q = 0; q < 4; ++q) acc[m][n][q] = 0.f;

  int aOff[4], bOff[4];
  #pragma unroll
  for (int m = 0; m < 4; ++m) aOff[m] = kb*2048 + (wr*64 + m*16 + lr)*16;
  #pragma unroll
  for (int n = 0; n < 4; ++n) bOff[n] = kb*2048 + (wc*64 + n*16 + lr)*16;

  // staging: 512 16B-chunks per tile; thread handles chunks t and t+256
  const int r0 = t & 127,        kb0 = t >> 7;
  const int r1 = (t+256) & 127,  kb1 = (t+256) >> 7;
  const size_t gA0 = (size_t)(rowBase + r0)*DIM + kb0*8;
  const size_t gA1 = (size_t)(rowBase + r1)*DIM + kb1*8;
  const size_t gB0 = (size_t)(colBase + r0)*DIM + kb0*8;
  const size_t gB1 = (size_t)(colBase + r1)*DIM + kb1*8;
  const int ld0 = t*16, ld1 = (t+256)*16;

  for (int k0 = 0; k0 < DIM; k0 += 32){
    gload16(Ah + gA0 + k0, smem + ld0);
    gload16(Ah + gA1 + k0, smem + ld1);
    gload16(Al + gA0 + k0, smem + 8192  + ld0);
    gload16(Al + gA1 + k0, smem + 8192  + ld1);
    gload16(Bh + gB0 + k0, smem + 16384 + ld0);
    gload16(Bh + gB1 + k0, smem + 16384 + ld1);
    gload16(Bl + gB0 + k0, smem + 24576 + ld0);
    gload16(Bl + gB1 + k0, smem + 24576 + ld1);
    __syncthreads();                      // drains vmcnt: LDS tiles ready
    bf16x8 ah[4], al[4];
    #pragma unroll
    for (int m = 0; m < 4; ++m){
      ah[m] = *(const bf16x8*)(smem + aOff[m]);
      al[m] = *(const bf16x8*)(smem + 8192 + aOff[m]);
    }
    #pragma unroll
    for (int n = 0; n < 4; ++n){
      bf16x8 bh = *(const bf16x8*)(smem + 16384 + bOff[n]);
      bf16x8 bl = *(const bf16x8*)(smem + 24576 + bOff[n]);
      #pragma unroll
      for (int m = 0; m < 4; ++m){
        acc[m][n] = __builtin_amdgcn_mfma_f32_16x16x32_bf16(ah[m], bh, acc[m][n], 0, 0, 0);
        acc[m][n] = __builtin_amdgcn_mfma_f32_16x16x32_bf16(ah[m], bl, acc[m][n], 0, 0, 0);
        acc[m][n] = __builtin_amdgcn_mfma_f32_16x16x32_bf16(al[m], bh, acc[m][n], 0, 0, 0);
      }
    }
    __syncthreads();                      // all reads done before next stage
  }

  // epilogue: C/D layout col=lane&15, row=(lane>>4)*4+reg  [m89/m91]
  float c2v[4], clv[4];
  #pragma unroll
  for (int n = 0; n < 4; ++n){
    int col = colBase + wc*64 + n*16 + lr;
    c2v[n] = cn2[col]; clv[n] = cl[col];
  }
  const int g4 = (l >> 4) * 4;
  #pragma unroll
  for (int m = 0; m < 4; ++m){
    int rbase = rowBase + wr*64 + m*16 + g4;
    #pragma unroll
    for (int q = 0; q < 4; ++q){
      float rn = rnorm[rbase + q];
      float bestv = INFINITY; int besti = 0x7fffffff;
      #pragma unroll
      for (int n = 0; n < 4; ++n){        // ascending col within lane
        float v = c2v[n] - 2.0f * rn * (acc[m][n][q] + clv[n]);  // padded: INF
        int ci = colBase + wc*64 + n*16 + lr;
        if (v < bestv){ bestv = v; besti = ci; }
      }
      #pragma unroll
      for (int mm = 1; mm < 16; mm <<= 1){  // reduce 16 lanes (same rows)
        float ov = __shfl_xor(bestv, mm, 64);
        int   oi = __shfl_xor(besti, mm, 64);
        if (ov < bestv || (ov == bestv && oi < besti)){ bestv = ov; besti = oi; }
      }
      if (lr == 0){
        int row = rbase + q;
        pval[row*16 + blockIdx.y*2 + wc] = bestv;
        pidx[row*16 + blockIdx.y*2 + wc] = besti;
      }
    }
  }
}

// ---------------- final argmin over NT tile partials -----------------------
template<int NT>
__global__ __launch_bounds__(256) void argmin_final(const float* __restrict__ pval,
    const int* __restrict__ pidx, const int* __restrict__ labels,
    int* __restrict__ out){
  const int i = blockIdx.x * 256 + threadIdx.x;
  float bestv = INFINITY; int besti = 0x7fffffff;
  #pragma unroll
  for (int s = 0; s < NT; ++s){
    float v = pval[i*NT + s]; int ix = pidx[i*NT + s];
    if (v < bestv || (v == bestv && ix < besti)){ bestv = v; besti = ix; }
  }
  out[i] = labels[besti];
}

// ==================== fp32 fallback path (verified round 8) ================
__global__ __launch_bounds__(256) void rnorm_kernel(const float* __restrict__ feats,
                                                    float* __restrict__ rnorm) {
    const int row = blockIdx.x;
    const int t = threadIdx.x;
    const float4* p4 = (const float4*)(feats + (size_t)row * DIM);
    float4 v0 = p4[t];
    float4 v1 = p4[t + 256];
    float s = v0.x*v0.x + v0.y*v0.y + v0.z*v0.z + v0.w*v0.w
            + v1.x*v1.x + v1.y*v1.y + v1.z*v1.z + v1.w*v1.w;
    #pragma unroll
    for (int m = 1; m < 64; m <<= 1) s += __shfl_xor(s, m, 64);
    __shared__ float ws[4];
    if ((t & 63) == 0) ws[t >> 6] = s;
    __syncthreads();
    if (t == 0) {
        float tot = ws[0] + ws[1] + ws[2] + ws[3] + 1.0f;
        rnorm[row] = 1.0f / sqrtf(tot);
    }
}

__global__ __launch_bounds__(256) void cn2_kernel(const float* __restrict__ initc,
                                                  float* __restrict__ cn2) {
    const int j = blockIdx.x;
    const int t = threadIdx.x;
    const float* p = initc + (size_t)j * CDIM;
    float s = 0.f;
    for (int i = t; i < CDIM; i += 256) { float v = p[i]; s = fmaf(v, v, s); }
    #pragma unroll
    for (int m = 1; m < 64; m <<= 1) s += __shfl_xor(s, m, 64);
    __shared__ float ws[4];
    if ((t & 63) == 0) ws[t >> 6] = s;
    __syncthreads();
    if (t == 0) cn2[j] = ws[0] + ws[1] + ws[2] + ws[3];
}

__global__ __launch_bounds__(256) void dist_kernel(const float* __restrict__ feats,
                                                   const float* __restrict__ initc,
                                                   const float* __restrict__ rnorm,
                                                   const float* __restrict__ cn2,
                                                   float* __restrict__ pval,
                                                   int* __restrict__ pidx) {
    __shared__ __align__(16) float As[16][128 + 4];
    __shared__ __align__(16) float Bs[16][128 + 4];
    const int bm = blockIdx.x;
    const int bn = blockIdx.y;
    const int t  = threadIdx.x;
    const int tx = t & 15;
    const int ty = t >> 4;
    const int rowBase  = bm * 128;
    const int centBase = bn * 128;
    float acc[8][8];
    #pragma unroll
    for (int i = 0; i < 8; ++i)
        #pragma unroll
        for (int j = 0; j < 8; ++j) acc[i][j] = 0.f;
    const int ar  = t >> 2;
    const int ac4 = (t & 3) << 2;
    const int bc  = t >> 4;
    const int bcol = t & 15;
    auto cidx = [&](int j) { return (j < 4) ? (tx * 4 + j) : (64 + tx * 4 + (j - 4)); };
    for (int k0 = 0; k0 < DIM; k0 += 16) {
        #pragma unroll
        for (int p = 0; p < 2; ++p) {
            int row = p * 64 + ar;
            const float4 v = *(const float4*)(feats + (size_t)(rowBase + row) * DIM + k0 + ac4);
            As[ac4 + 0][row] = v.x;
            As[ac4 + 1][row] = v.y;
            As[ac4 + 2][row] = v.z;
            As[ac4 + 3][row] = v.w;
        }
        #pragma unroll
        for (int p = 0; p < 8; ++p) {
            int cent = p * 16 + bc;
            int gj = centBase + cent;
            Bs[bcol][cent] = (gj < K_CENT) ? initc[(size_t)gj * CDIM + k0 + bcol] : 0.f;
        }
        __syncthreads();
        #pragma unroll
        for (int kk = 0; kk < 16; ++kk) {
            float a[8], b[8];
            *(float4*)&a[0] = *(const float4*)&As[kk][ty * 8];
            *(float4*)&a[4] = *(const float4*)&As[kk][ty * 8 + 4];
            *(float4*)&b[0] = *(const float4*)&Bs[kk][tx * 4];
            *(float4*)&b[4] = *(const float4*)&Bs[kk][64 + tx * 4];
            #pragma unroll
            for (int i = 0; i < 8; ++i)
                #pragma unroll
                for (int j = 0; j < 8; ++j)
                    acc[i][j] = fmaf(a[i], b[j], acc[i][j]);
        }
        __syncthreads();
    }
    float rn[8];
    #pragma unroll
    for (int i = 0; i < 8; ++i) rn[i] = rnorm[rowBase + ty * 8 + i];
    float cle[8], c2[8];
    #pragma unroll
    for (int j = 0; j < 8; ++j) {
        int gj = centBase + cidx(j);
        cle[j] = (gj < K_CENT) ? initc[(size_t)gj * CDIM + DIM] : 0.f;
        c2[j] = (gj < K_CENT) ? cn2[gj] : INFINITY;
    }
    #pragma unroll
    for (int i = 0; i < 8; ++i) {
        float bestv = INFINITY;
        int   besti = 0x7fffffff;
        #pragma unroll
        for (int j = 0; j < 8; ++j) {
            int gj = centBase + cidx(j);
            float v = (gj < K_CENT) ? (c2[j] - 2.0f * rn[i] * (acc[i][j] + cle[j])) : INFINITY;
            if (v < bestv) { bestv = v; besti = gj; }
        }
        #pragma unroll
        for (int m = 1; m < 16; m <<= 1) {
            float ov = __shfl_xor(bestv, m, 64);
            int   oi = __shfl_xor(besti, m, 64);
            if (ov < bestv || (ov == bestv && oi < besti)) { bestv = ov; besti = oi; }
        }
        if (tx == 0) {
            int row = rowBase + ty * 8 + i;
            pval[row * 8 + bn] = bestv;
            pidx[row * 8 + bn] = besti;
        }
    }
}

// ==================== launch ==============================================
extern "C" void kernel_launch(void* const* d_in, const int* in_sizes, int n_in,
                              void* d_out, int out_size, void* d_ws, size_t ws_size,
                              hipStream_t stream) {
    const float* feats  = (const float*)d_in[0];   // [16384, 2048] fp32
    const float* initc  = (const float*)d_in[1];   // [1000, 2049] fp32
    const int*   labels = (const int*)d_in[2];     // [1000] int32 (arange)
    int* out = (int*)d_out;                        // [16384] int32
    char* ws = (char*)d_ws;

    if (ws_size >= WS_NEED) {
        // -------- bf16x3 MFMA path --------
        unsigned short* Ah = (unsigned short*)(ws + WS_AH);
        unsigned short* Al = (unsigned short*)(ws + WS_AL);
        unsigned short* Bh = (unsigned short*)(ws + WS_BH);
        unsigned short* Bl = (unsigned short*)(ws + WS_BL);
        float* rn  = (float*)(ws + WS_RN);
        float* c2  = (float*)(ws + WS_CN2);
        float* clp = (float*)(ws + WS_CL);
        float* pv  = (float*)(ws + WS_PV);
        int*   pi  = (int*)  (ws + WS_PI);

        prep_feats<<<N_ROWS, 256, 0, stream>>>(feats, Ah, Al, rn);
        prep_cent<<<KPAD, 256, 0, stream>>>(initc, Bh, Bl, c2, clp);
        dim3 grid(N_ROWS / 128, KPAD / 128);
        dist_mfma<<<grid, 256, 0, stream>>>(Ah, Al, Bh, Bl, rn, c2, clp, pv, pi);
        argmin_final<16><<<N_ROWS / 256, 256, 0, stream>>>(pv, pi, labels, out);
    } else {
        // -------- fp32 fallback (verified) --------
        float* rnorm = (float*)(ws);
        float* cn2   = (float*)(ws + 65536);
        float* pval  = (float*)(ws + 73728);
        int*   pidx  = (int*)  (ws + 73728 + 524288);

        rnorm_kernel<<<N_ROWS, 256, 0, stream>>>(feats, rnorm);
        cn2_kernel<<<K_CENT, 256, 0, stream>>>(initc, cn2);
        dim3 grid(N_ROWS / 128, 8);
        dist_kernel<<<grid, 256, 0, stream>>>(feats, initc, rnorm, cn2, pval, pidx);
        argmin_final<8><<<N_ROWS / 256, 256, 0, stream>>>(pval, pidx, labels, out);
    }
}